// Round 1
// baseline (128.516 us; speedup 1.0000x reference)
//
#include <hip/hip_runtime.h>
#include <hip/hip_bf16.h>

#define P_ADC 64
#define M_SEN 256
#define B_BLK 32
#define BATCHN 4096

// Derived GEMM shape: Out[R=131072][128] = X[R][512] * W[512][128], W[k][p] = A[p][k]
#define GK 512
#define GN 128
#define GR (BATCHN * B_BLK)   // 131072 rows

typedef float  f32x4  __attribute__((ext_vector_type(4)));
typedef __bf16 bf16x8 __attribute__((ext_vector_type(8)));

// ---------------------------------------------------------------------------
// Kernel 1: build W in MFMA B-fragment order.
// Layout: wfrag[t][f][lane][j] (bf16), t=K-step (0..15), f=N-frag (0..7),
//   maps to B[k][n] with k = t*32 + (lane>>4)*8 + j, n = f*16 + (lane&15).
// W[k][n] = A[n][k]:
//   A[p][m]: p<64,m<256 -> cos ; p<64,m>=256 -> -sin ; p>=64,m<256 -> sin ;
//            p>=64,m>=256 -> cos   (ang = -pv[p&63] * (m&255) * 2pi/256)
// ---------------------------------------------------------------------------
__global__ void build_w_frags(const float* __restrict__ pv, __bf16* __restrict__ wfrag) {
    int tid = blockIdx.x * blockDim.x + threadIdx.x;
    if (tid >= 16 * 8 * 64) return;
    int lane = tid & 63;
    int f    = (tid >> 6) & 7;
    int t    = tid >> 9;
    int n    = f * 16 + (lane & 15);
    int kb   = t * 32 + (lane >> 4) * 8;
    int q    = n & 63;
    bool ph  = (n >= 64);
    float pq = pv[q];
    const float step = -0.02454369260617025967f; // -2*pi/256
    bf16x8 v;
#pragma unroll
    for (int j = 0; j < 8; ++j) {
        int k  = kb + j;
        int mm = k & 255;
        bool mh = (k >= 256);
        float ang = pq * (float)mm * step;
        float s, c;
        sincosf(ang, &s, &c);
        float a = (ph == mh) ? c : (ph ? s : -s);
        v[j] = (__bf16)a;
    }
    *(bf16x8*)(wfrag + (size_t)tid * 8) = v;
}

// ---------------------------------------------------------------------------
// Kernel 2: streaming MFMA GEMM. 256 threads = 4 waves; block does 128 rows,
// wave does 32 rows x all 128 cols. No LDS, no barriers.
// ---------------------------------------------------------------------------
__global__ __launch_bounds__(256) void analog_gemm(const float* __restrict__ X,
                                                   const __bf16* __restrict__ W,
                                                   float* __restrict__ out) {
    const int lane = threadIdx.x & 63;
    const int wave = threadIdx.x >> 6;
    const long rowbase = (long)blockIdx.x * 128 + (long)wave * 32;

    const int lr = lane & 15;
    const int lk = (lane >> 4) * 8;

    const float* x0 = X + (rowbase + lr) * (long)GK + lk;       // rows 0..15 of stripe
    const float* x1 = x0 + 16L * GK;                            // rows 16..31
    const bf16x8* wp = (const bf16x8*)W + lane;                 // + (t*8+f)*64

    f32x4 acc[2][8];
#pragma unroll
    for (int rf = 0; rf < 2; ++rf)
#pragma unroll
        for (int f = 0; f < 8; ++f)
            acc[rf][f] = (f32x4)0.0f;

#pragma unroll
    for (int t = 0; t < 16; ++t) {
        f32x4 xa0 = *(const f32x4*)(x0 + t * 32);
        f32x4 xb0 = *(const f32x4*)(x0 + t * 32 + 4);
        f32x4 xa1 = *(const f32x4*)(x1 + t * 32);
        f32x4 xb1 = *(const f32x4*)(x1 + t * 32 + 4);

        bf16x8 a0, a1;
#pragma unroll
        for (int j = 0; j < 4; ++j) {
            a0[j]     = (__bf16)xa0[j];
            a0[4 + j] = (__bf16)xb0[j];
            a1[j]     = (__bf16)xa1[j];
            a1[4 + j] = (__bf16)xb1[j];
        }

#pragma unroll
        for (int f = 0; f < 8; ++f) {
            bf16x8 b = wp[(t * 8 + f) * 64];
            acc[0][f] = __builtin_amdgcn_mfma_f32_16x16x32_bf16(a0, b, acc[0][f], 0, 0, 0);
            acc[1][f] = __builtin_amdgcn_mfma_f32_16x16x32_bf16(a1, b, acc[1][f], 0, 0, 0);
        }
    }

    // C/D layout (m89): col = lane&15, row = (lane>>4)*4 + reg
    const int orow = (lane >> 4) * 4;
    const int ocol = lane & 15;
#pragma unroll
    for (int rf = 0; rf < 2; ++rf)
#pragma unroll
        for (int f = 0; f < 8; ++f)
#pragma unroll
            for (int r = 0; r < 4; ++r)
                out[(rowbase + rf * 16 + orow + r) * (long)GN + f * 16 + ocol] = acc[rf][f][r];
}

extern "C" void kernel_launch(void* const* d_in, const int* in_sizes, int n_in,
                              void* d_out, int out_size, void* d_ws, size_t ws_size,
                              hipStream_t stream) {
    const float* x  = (const float*)d_in[0];
    const float* pv = (const float*)d_in[1];
    float* out      = (float*)d_out;
    __bf16* wfrag   = (__bf16*)d_ws;   // needs 16*8*64*8*2 = 131072 bytes

    hipLaunchKernelGGL(build_w_frags, dim3(32), dim3(256), 0, stream, pv, wfrag);
    hipLaunchKernelGGL(analog_gemm, dim3(GR / 128), dim3(256), 0, stream, x, wfrag, out);
}

// Round 2
// 85.211 us; speedup vs baseline: 1.5082x; 1.5082x over previous
//
#include <hip/hip_runtime.h>
#include <hip/hip_bf16.h>

#define P_ADC 64
#define M_SEN 256
#define B_BLK 32
#define BATCHN 4096

// Derived GEMM: Out[R=131072][128] = X[R][512] * W[512][128], W[k][p] = A[p][k]
#define GK 512
#define GN 128
#define GR (BATCHN * B_BLK)   // 131072 rows

typedef float  f32x4  __attribute__((ext_vector_type(4)));
typedef __bf16 bf16x8 __attribute__((ext_vector_type(8)));

// ---------------------------------------------------------------------------
// Kernel 1: build W in MFMA fragment order (valid as either A- or B-operand,
// layouts are symmetric): wfrag[t][f][lane][j] (bf16) holds
//   W[k][n],  k = t*32 + (lane>>4)*8 + j,  n = f*16 + (lane&15)
// W[k][n] = A[n][k]:
//   A[p][m]: p<64,m<256 -> cos ; p<64,m>=256 -> -sin ; p>=64,m<256 -> sin ;
//            p>=64,m>=256 -> cos   (ang = -pv[p&63] * (m&255) * 2pi/256)
// ---------------------------------------------------------------------------
__global__ void build_w_frags(const float* __restrict__ pv, __bf16* __restrict__ wfrag) {
    int tid = blockIdx.x * blockDim.x + threadIdx.x;
    if (tid >= 16 * 8 * 64) return;
    int lane = tid & 63;
    int f    = (tid >> 6) & 7;
    int t    = tid >> 9;
    int n    = f * 16 + (lane & 15);
    int kb   = t * 32 + (lane >> 4) * 8;
    int q    = n & 63;
    bool ph  = (n >= 64);
    float pq = pv[q];
    const float step = -0.02454369260617025967f; // -2*pi/256
    bf16x8 v;
#pragma unroll
    for (int j = 0; j < 8; ++j) {
        int k  = kb + j;
        int mm = k & 255;
        bool mh = (k >= 256);
        float ang = pq * (float)mm * step;
        float s, c;
        sincosf(ang, &s, &c);
        float a = (ph == mh) ? c : (ph ? s : -s);
        v[j] = (__bf16)a;
    }
    *(bf16x8*)(wfrag + (size_t)tid * 8) = v;
}

// ---------------------------------------------------------------------------
// Kernel 2: streaming MFMA GEMM. 2048 blocks x 256 thr (4 waves). Wave does
// 16 rows x 128 cols. Operands SWAPPED vs naive: A=W, B=X, so
//   D[i][j] = sum_k W[k][f*16+i] * X[rowbase+j][k]  -> i=out col, j=out row
// D layout (m89): reg r = D[(lane>>4)*4 + r][lane&15]
//   -> lane holds 4 CONSECUTIVE out cols at one row => f32x4 store.
// No LDS, no barriers.
// ---------------------------------------------------------------------------
__global__ __launch_bounds__(256, 4) void analog_gemm(const float* __restrict__ X,
                                                      const __bf16* __restrict__ W,
                                                      float* __restrict__ out) {
    const int lane = threadIdx.x & 63;
    const int wave = threadIdx.x >> 6;
    const long rowbase = (long)blockIdx.x * 64 + (long)wave * 16;

    const int lr = lane & 15;          // X row within stripe (B-frag 16-dim)
    const int lk = (lane >> 4) * 8;    // K sub-offset

    const float* xp = X + (rowbase + lr) * (long)GK + lk;
    const bf16x8* wp = (const bf16x8*)W + lane;   // + (t*8+f)*64

    f32x4 acc[8];
#pragma unroll
    for (int f = 0; f < 8; ++f) acc[f] = (f32x4)0.0f;

#pragma unroll
    for (int t = 0; t < 16; ++t) {
        f32x4 xa = *(const f32x4*)(xp + t * 32);
        f32x4 xb = *(const f32x4*)(xp + t * 32 + 4);

        bf16x8 b;
#pragma unroll
        for (int j = 0; j < 4; ++j) {
            b[j]     = (__bf16)xa[j];
            b[4 + j] = (__bf16)xb[j];
        }

#pragma unroll
        for (int f = 0; f < 8; ++f) {
            bf16x8 w = wp[(t * 8 + f) * 64];
            acc[f] = __builtin_amdgcn_mfma_f32_16x16x32_bf16(w, b, acc[f], 0, 0, 0);
        }
    }

    // lane stores row rowbase+(lane&15), cols f*16 + (lane>>4)*4 .. +3
    float* op = out + (rowbase + lr) * (long)GN + (lane >> 4) * 4;
#pragma unroll
    for (int f = 0; f < 8; ++f)
        __builtin_nontemporal_store(acc[f], (f32x4*)(op + f * 16));
}

extern "C" void kernel_launch(void* const* d_in, const int* in_sizes, int n_in,
                              void* d_out, int out_size, void* d_ws, size_t ws_size,
                              hipStream_t stream) {
    const float* x  = (const float*)d_in[0];
    const float* pv = (const float*)d_in[1];
    float* out      = (float*)d_out;
    __bf16* wfrag   = (__bf16*)d_ws;   // 16*8*64*8*2 = 131072 bytes

    hipLaunchKernelGGL(build_w_frags, dim3(32), dim3(256), 0, stream, pv, wfrag);
    hipLaunchKernelGGL(analog_gemm, dim3(GR / 64), dim3(256), 0, stream, x, wfrag, out);
}

// Round 3
// 69.997 us; speedup vs baseline: 1.8360x; 1.2174x over previous
//
#include <hip/hip_runtime.h>
#include <hip/hip_bf16.h>

#define P_ADC 64
#define M_SEN 256
#define B_BLK 32
#define BATCHN 4096

// Derived GEMM: Out[R=131072][128] = X[R][512] * W[512][128], W[k][p] = A[p][k]
#define GK 512
#define GN 128
#define GR (BATCHN * B_BLK)   // 131072 rows

typedef float  f32x4  __attribute__((ext_vector_type(4)));
typedef __bf16 bf16x8 __attribute__((ext_vector_type(8)));

// ---------------------------------------------------------------------------
// Kernel 1: build W in MFMA fragment order (A/B layouts symmetric):
// wfrag[t][f][lane][j] (bf16) holds
//   W[k][n],  k = t*32 + (lane>>4)*8 + j,  n = f*16 + (lane&15)
// W[k][n] = A[n][k]:
//   A[p][m]: p<64,m<256 -> cos ; p<64,m>=256 -> -sin ; p>=64,m<256 -> sin ;
//            p>=64,m>=256 -> cos   (ang = -pv[p&63] * (m&255) * 2pi/256)
// ---------------------------------------------------------------------------
__global__ void build_w_frags(const float* __restrict__ pv, __bf16* __restrict__ wfrag) {
    int tid = blockIdx.x * blockDim.x + threadIdx.x;
    if (tid >= 16 * 8 * 64) return;
    int lane = tid & 63;
    int f    = (tid >> 6) & 7;
    int t    = tid >> 9;
    int n    = f * 16 + (lane & 15);
    int kb   = t * 32 + (lane >> 4) * 8;
    int q    = n & 63;
    bool ph  = (n >= 64);
    float pq = pv[q];
    const float step = -0.02454369260617025967f; // -2*pi/256
    bf16x8 v;
#pragma unroll
    for (int j = 0; j < 8; ++j) {
        int k  = kb + j;
        int mm = k & 255;
        bool mh = (k >= 256);
        float ang = pq * (float)mm * step;
        float s, c;
        sincosf(ang, &s, &c);
        float a = (ph == mh) ? c : (ph ? s : -s);
        v[j] = (__bf16)a;
    }
    *(bf16x8*)(wfrag + (size_t)tid * 8) = v;
}

// ---------------------------------------------------------------------------
// Kernel 2: W staged in LDS (128 KB, once per block), X streamed from HBM.
// 1024 threads = 16 waves, wave does 16 rows x 128 cols, block = 256 rows.
// Grid = 512 = 2 rounds/CU (1 block/CU due to LDS). Swapped operands:
//   D[i][j] = sum_k W[k][f*16+i] * X[rowbase+j][k]  -> reg r = out col, f32x4 store.
// ---------------------------------------------------------------------------
__global__ __launch_bounds__(1024) void analog_gemm(const float* __restrict__ X,
                                                    const __bf16* __restrict__ W,
                                                    float* __restrict__ out) {
    __shared__ __bf16 lw[16 * 8 * 64 * 8];   // 65536 bf16 = 128 KB

    const int tid = threadIdx.x;

    // Stage W global->LDS: 8192 x 16B chunks, 1024 threads x 8 chunks each.
    {
        const f32x4* src = (const f32x4*)W;
        f32x4* dst = (f32x4*)lw;
#pragma unroll
        for (int i = 0; i < 8; ++i)
            dst[i * 1024 + tid] = src[i * 1024 + tid];
    }
    __syncthreads();

    const int lane = tid & 63;
    const int wave = tid >> 6;
    const long rowbase = (long)blockIdx.x * 256 + (long)wave * 16;

    const int lr = lane & 15;          // X row within stripe (B-frag 16-dim)
    const int lk = (lane >> 4) * 8;    // K sub-offset

    const float* xp = X + (rowbase + lr) * (long)GK + lk;
    const bf16x8* wp = (const bf16x8*)lw + lane;   // + (t*8+f)*64

    f32x4 acc[8];
#pragma unroll
    for (int f = 0; f < 8; ++f) acc[f] = (f32x4)0.0f;

#pragma unroll
    for (int t = 0; t < 16; ++t) {
        f32x4 xa = *(const f32x4*)(xp + t * 32);
        f32x4 xb = *(const f32x4*)(xp + t * 32 + 4);

        bf16x8 b;
#pragma unroll
        for (int j = 0; j < 4; ++j) {
            b[j]     = (__bf16)xa[j];
            b[4 + j] = (__bf16)xb[j];
        }

#pragma unroll
        for (int f = 0; f < 8; ++f) {
            bf16x8 w = wp[(t * 8 + f) * 64];
            acc[f] = __builtin_amdgcn_mfma_f32_16x16x32_bf16(w, b, acc[f], 0, 0, 0);
        }
    }

    // lane stores row rowbase+(lane&15), cols f*16 + (lane>>4)*4 .. +3
    float* op = out + (rowbase + lr) * (long)GN + (lane >> 4) * 4;
#pragma unroll
    for (int f = 0; f < 8; ++f)
        __builtin_nontemporal_store(acc[f], (f32x4*)(op + f * 16));
}

extern "C" void kernel_launch(void* const* d_in, const int* in_sizes, int n_in,
                              void* d_out, int out_size, void* d_ws, size_t ws_size,
                              hipStream_t stream) {
    const float* x  = (const float*)d_in[0];
    const float* pv = (const float*)d_in[1];
    float* out      = (float*)d_out;
    __bf16* wfrag   = (__bf16*)d_ws;   // 16*8*64*8*2 = 131072 bytes

    hipLaunchKernelGGL(build_w_frags, dim3(32), dim3(256), 0, stream, pv, wfrag);
    hipLaunchKernelGGL(analog_gemm, dim3(GR / 256), dim3(1024), 0, stream, x, wfrag, out);
}